// Round 1
// baseline (192.144 us; speedup 1.0000x reference)
//
#include <hip/hip_runtime.h>
#include <hip/hip_bf16.h>
#include <stdint.h>

#define SDIM 1024
#define BATCH 4
#define NH 16
#define HDIM 64
#define KDIM 1024
#define N_QKV 3072
#define EMB 1024

typedef uint16_t u16;
typedef __attribute__((ext_vector_type(4))) float f32x4;
typedef __attribute__((ext_vector_type(8))) short bf16x8;
typedef __attribute__((ext_vector_type(8))) unsigned short u16x8;

__device__ __forceinline__ u16 f2bf(float f) {
  union { float f; uint32_t u; } x; x.f = f;
  uint32_t r = x.u + 0x7FFFu + ((x.u >> 16) & 1u);
  return (u16)(r >> 16);
}

__device__ __forceinline__ float bf2f(u16 b) {
  union { uint32_t u; float f; } x; x.u = ((uint32_t)b) << 16;
  return x.f;
}

__device__ __forceinline__ void gload_lds16(const u16* g, u16* l) {
  __builtin_amdgcn_global_load_lds(
      (const __attribute__((address_space(1))) unsigned int*)g,
      (__attribute__((address_space(3))) unsigned int*)l, 16, 0, 0);
}

// ---------------- f32 -> bf16 conversion (memory-bound) ----------------
__global__ void cvt_bf16_kernel(const float* __restrict__ src, u16* __restrict__ dst, int n8) {
  int stride = gridDim.x * blockDim.x;
  for (int i = blockIdx.x * blockDim.x + threadIdx.x; i < n8; i += stride) {
    const float4* s4 = (const float4*)src + (size_t)i * 2;
    float4 a = s4[0], b = s4[1];
    u16x8 o;
    o[0] = f2bf(a.x); o[1] = f2bf(a.y); o[2] = f2bf(a.z); o[3] = f2bf(a.w);
    o[4] = f2bf(b.x); o[5] = f2bf(b.y); o[6] = f2bf(b.z); o[7] = f2bf(b.w);
    ((u16x8*)dst)[i] = o;
  }
}

// ---------------- GEMM: C[M][N] = A[M][K] * B[N][K]^T + bias ----------------
// A, B bf16 row-major K-contiguous. 128x128 tile, BK=64, 4 waves, 16x16x32 MFMA.
template<bool OUTBF16>
__global__ __launch_bounds__(256) void gemm_bt(
    const u16* __restrict__ A, const u16* __restrict__ Bm,
    const float* __restrict__ bias, void* __restrict__ Cv,
    int M, int N, int K)
{
  __shared__ u16 As[128 * 64];
  __shared__ u16 Bs[128 * 64];
  const int tid = threadIdx.x;
  const int wid = tid >> 6, lane = tid & 63;
  const int g = lane >> 4, c = lane & 15;
  const int wrow = (wid >> 1) * 64, wcol = (wid & 1) * 64;
  const int brow = blockIdx.x * 128, bcol = blockIdx.y * 128;

  f32x4 acc[4][4] = {};

  const int nkt = K >> 6;
  for (int kt = 0; kt < nkt; ++kt) {
    #pragma unroll
    for (int j = 0; j < 4; ++j) {
      int ci = j * 256 + tid;           // 16B chunk index (per-lane, for global addr)
      int r = ci >> 3, c8 = ci & 7;
      // LDS dest base is wave-uniform; HW adds lane*16
      gload_lds16(A  + (size_t)(brow + r) * K + kt * 64 + c8 * 8,
                  As + (size_t)(j * 256 + wid * 64) * 8);
      gload_lds16(Bm + (size_t)(bcol + r) * K + kt * 64 + c8 * 8,
                  Bs + (size_t)(j * 256 + wid * 64) * 8);
    }
    __syncthreads();

    bf16x8 af[2][4], bfr[2][4];
    #pragma unroll
    for (int kk = 0; kk < 2; ++kk) {
      #pragma unroll
      for (int i = 0; i < 4; ++i) {
        af[kk][i]  = *(const bf16x8*)&As[(wrow + i * 16 + c) * 64 + kk * 32 + g * 8];
        bfr[kk][i] = *(const bf16x8*)&Bs[(wcol + i * 16 + c) * 64 + kk * 32 + g * 8];
      }
    }
    #pragma unroll
    for (int kk = 0; kk < 2; ++kk)
      #pragma unroll
      for (int mi = 0; mi < 4; ++mi)
        #pragma unroll
        for (int ni = 0; ni < 4; ++ni)
          acc[mi][ni] = __builtin_amdgcn_mfma_f32_16x16x32_bf16(
              af[kk][mi], bfr[kk][ni], acc[mi][ni], 0, 0, 0);
    __syncthreads();
  }

  #pragma unroll
  for (int mi = 0; mi < 4; ++mi) {
    #pragma unroll
    for (int ni = 0; ni < 4; ++ni) {
      int col = bcol + wcol + ni * 16 + c;
      float bv = bias[col];
      #pragma unroll
      for (int r = 0; r < 4; ++r) {
        int row = brow + wrow + mi * 16 + g * 4 + r;
        float v = acc[mi][ni][r] + bv;
        if (OUTBF16) ((u16*)Cv)[(size_t)row * N + col] = f2bf(v);
        else         ((float*)Cv)[(size_t)row * N + col] = v;
      }
    }
  }
}

// ---------------- fused masked+weighted flash attention ----------------
// qkv: [B*S][3072] bf16, head h: q at h*192, k at h*192+64, v at h*192+128
// mask: [B][S][S] int, wts: [B][S][S] f32 (consumed transposed)
// vals: [B*S][1024] bf16 out
__global__ __launch_bounds__(256) void attn_kernel(
    const u16* __restrict__ qkv, const int* __restrict__ mask,
    const float* __restrict__ wts, u16* __restrict__ vals)
{
  const int qt = blockIdx.x, h = blockIdx.y, b = blockIdx.z;
  const int tid = threadIdx.x;
  const int wid = tid >> 6, lane = tid & 63;
  const int g = lane >> 4, c = lane & 15;
  const int qloc = qt * 64 + wid * 16;   // wave's first q row (within S)

  __shared__ u16 Vt[64][72];             // V^T tile: [d][k], pad 8 -> conflict-light
  __shared__ u16 Plds[4][16][72];        // per-wave P tile [qrow][k]

  // Q A-fragments (held all loop)
  const u16* qp = qkv + (size_t)(b * SDIM + qloc + c) * N_QKV + h * 192;
  bf16x8 qa0 = *(const bf16x8*)(qp + g * 8);
  bf16x8 qa1 = *(const bf16x8*)(qp + 32 + g * 8);

  float m_run[4], l_run[4];
  f32x4 acc_o[4] = {};
  #pragma unroll
  for (int r = 0; r < 4; ++r) { m_run[r] = -1e30f; l_run[r] = 0.f; }

  for (int kt = 0; kt < 16; ++kt) {
    const int k0 = kt * 64;
    __syncthreads();   // previous PV reads done before restaging Vt

    // cooperative stage V^T (64 k-rows x 64 d)
    #pragma unroll
    for (int jj = 0; jj < 2; ++jj) {
      int ci = tid * 2 + jj;
      int kr = ci >> 3, d0 = (ci & 7) * 8;
      bf16x8 v = *(const bf16x8*)(qkv + (size_t)(b * SDIM + k0 + kr) * N_QKV + h * 192 + 128 + d0);
      #pragma unroll
      for (int e = 0; e < 8; ++e) Vt[d0 + e][kr] = (u16)v[e];
    }

    // QK^T: 4 subtiles of 16 k-cols
    f32x4 sc[4];
    #pragma unroll
    for (int st = 0; st < 4; ++st) {
      const u16* kp = qkv + (size_t)(b * SDIM + k0 + st * 16 + c) * N_QKV + h * 192 + 64;
      bf16x8 kb0 = *(const bf16x8*)(kp + g * 8);
      bf16x8 kb1 = *(const bf16x8*)(kp + 32 + g * 8);
      f32x4 z = {};
      z = __builtin_amdgcn_mfma_f32_16x16x32_bf16(qa0, kb0, z, 0, 0, 0);
      z = __builtin_amdgcn_mfma_f32_16x16x32_bf16(qa1, kb1, z, 0, 0, 0);
      sc[st] = z;
    }

    // scale + mask + transposed weights; online weighted softmax
    float sv[4][4], w4v[4][4];           // [st][reg]
    #pragma unroll
    for (int st = 0; st < 4; ++st) {
      int k = k0 + st * 16 + c;
      float4 w4 = *(const float4*)(wts + (size_t)b * SDIM * SDIM + (size_t)k * SDIM + qloc + g * 4);
      const int* mp = mask + (size_t)b * SDIM * SDIM + (size_t)(qloc + g * 4) * SDIM + k;
      #pragma unroll
      for (int r = 0; r < 4; ++r) {
        float s = sc[st][r] * 0.125f;
        if (mp[r * SDIM] == 0) s = -9e15f;
        sv[st][r] = s;
        w4v[st][r] = ((const float*)&w4)[r];
      }
    }
    #pragma unroll
    for (int r = 0; r < 4; ++r) {
      float tm = fmaxf(fmaxf(sv[0][r], sv[1][r]), fmaxf(sv[2][r], sv[3][r]));
      #pragma unroll
      for (int o = 1; o < 16; o <<= 1) tm = fmaxf(tm, __shfl_xor(tm, o));
      float mn = fmaxf(m_run[r], tm);
      float fac = __expf(m_run[r] - mn);
      m_run[r] = mn;
      l_run[r] *= fac;
      #pragma unroll
      for (int dt = 0; dt < 4; ++dt) acc_o[dt][r] *= fac;
      #pragma unroll
      for (int st = 0; st < 4; ++st) {
        float p = w4v[st][r] * __expf(sv[st][r] - mn);
        u16 pb = f2bf(p);
        l_run[r] += bf2f(pb);            // denominator consistent with bf16 numerator
        Plds[wid][g * 4 + r][st * 16 + c] = pb;
      }
    }
    __syncthreads();   // Vt staged by all, P written

    // PV: re-fragment P from LDS, V^T fragments from LDS
    bf16x8 pa0 = *(const bf16x8*)&Plds[wid][c][g * 8];
    bf16x8 pa1 = *(const bf16x8*)&Plds[wid][c][32 + g * 8];
    #pragma unroll
    for (int dt = 0; dt < 4; ++dt) {
      bf16x8 vb0 = *(const bf16x8*)&Vt[dt * 16 + c][g * 8];
      bf16x8 vb1 = *(const bf16x8*)&Vt[dt * 16 + c][32 + g * 8];
      acc_o[dt] = __builtin_amdgcn_mfma_f32_16x16x32_bf16(pa0, vb0, acc_o[dt], 0, 0, 0);
      acc_o[dt] = __builtin_amdgcn_mfma_f32_16x16x32_bf16(pa1, vb1, acc_o[dt], 0, 0, 0);
    }
  }

  // finalize: reduce l across the 16-lane group, divide, store bf16
  #pragma unroll
  for (int r = 0; r < 4; ++r)
    #pragma unroll
    for (int o = 1; o < 16; o <<= 1) l_run[r] += __shfl_xor(l_run[r], o);

  #pragma unroll
  for (int dt = 0; dt < 4; ++dt) {
    #pragma unroll
    for (int r = 0; r < 4; ++r) {
      float v = acc_o[dt][r] / l_run[r];
      int row = b * SDIM + qloc + g * 4 + r;
      vals[(size_t)row * EMB + h * HDIM + dt * 16 + c] = f2bf(v);
    }
  }
}

extern "C" void kernel_launch(void* const* d_in, const int* in_sizes, int n_in,
                              void* d_out, int out_size, void* d_ws, size_t ws_size,
                              hipStream_t stream) {
  const float* x     = (const float*)d_in[0];
  const int*   mask  = (const int*)d_in[1];
  const float* wts   = (const float*)d_in[2];
  const float* W_qkv = (const float*)d_in[3];
  const float* b_qkv = (const float*)d_in[4];
  const float* W_o   = (const float*)d_in[5];
  const float* b_o   = (const float*)d_in[6];
  float* out = (float*)d_out;

  char* ws = (char*)d_ws;
  u16* xb   = (u16*)(ws);                     //  8 MB: x bf16 [4096][1024]
  u16* wqb  = (u16*)(ws + (8ull  << 20));     //  6 MB: W_qkv bf16 [3072][1024]
  u16* wob  = (u16*)(ws + (14ull << 20));     //  2 MB: W_o bf16 [1024][1024]
  u16* qkvb = (u16*)(ws + (16ull << 20));     // 24 MB: qkv bf16 [4096][3072]
  u16* valb = (u16*)(ws + (40ull << 20));     //  8 MB: attn out bf16 [4096][1024]

  cvt_bf16_kernel<<<2048, 256, 0, stream>>>(x,     xb,  (BATCH * SDIM * KDIM) / 8);
  cvt_bf16_kernel<<<1536, 256, 0, stream>>>(W_qkv, wqb, (N_QKV * KDIM) / 8);
  cvt_bf16_kernel<<<512,  256, 0, stream>>>(W_o,   wob, (EMB * EMB) / 8);

  dim3 g1(32, 24);   // M=4096/128, N=3072/128
  gemm_bt<true><<<g1, 256, 0, stream>>>(xb, wqb, b_qkv, qkvb, BATCH * SDIM, N_QKV, KDIM);

  dim3 g2(16, 16, 4);  // qtile, head, batch
  attn_kernel<<<g2, 256, 0, stream>>>(qkvb, mask, wts, valb);

  dim3 g3(32, 8);    // M=4096/128, N=1024/128
  gemm_bt<false><<<g3, 256, 0, stream>>>(valb, wob, b_o, out, BATCH * SDIM, EMB, KDIM);
}